// Round 13
// baseline (1130.235 us; speedup 1.0000x reference)
//
#include <hip/hip_runtime.h>
#include <stdint.h>

#define B_ROWS 16384
#define E_DIM 1024
#define H_N 16

typedef unsigned short u16;
typedef __attribute__((ext_vector_type(4))) float f32x4;
typedef __attribute__((ext_vector_type(4))) unsigned short u16x4;
typedef __attribute__((ext_vector_type(8))) short bf16x8;

static __device__ __forceinline__ u16 f2bf(float f) {
  union { float f; unsigned u; } x; x.f = f;
  unsigned r = (x.u + 0x7FFFu + ((x.u >> 16) & 1u)) >> 16;
  return (u16)r;
}
static __device__ __forceinline__ float bf2f(u16 h) {
  union { unsigned u; float f; } x; x.u = ((unsigned)h) << 16;
  return x.f;
}

typedef const __attribute__((address_space(1))) void gvoid;
typedef __attribute__((address_space(3))) void lvoid;
static __device__ __forceinline__ void gload16(const void* g, void* l) {
  __builtin_amdgcn_global_load_lds((gvoid*)g, (lvoid*)l, 16, 0, 0);
}

// ---------------- f32 -> bf16 convert (single buffer) ----------------
__global__ __launch_bounds__(256) void cvt_f32_bf16(const float* __restrict__ in,
                                                    u16* __restrict__ out, int n4) {
  int stride = gridDim.x * blockDim.x;
  for (int i = blockIdx.x * blockDim.x + threadIdx.x; i < n4; i += stride) {
    f32x4 v = ((const f32x4*)in)[i];
    u16x4 o;
    o.x = f2bf(v.x); o.y = f2bf(v.y); o.z = f2bf(v.z); o.w = f2bf(v.w);
    ((u16x4*)out)[i] = o;
  }
}

// ---------------- build ALL THREE Wcat_j = [wq_j ; wkv_o0 ; wkv_o1] in one launch
__global__ __launch_bounds__(256) void cvt_wcat(const float* __restrict__ w0,
                                                const float* __restrict__ w1,
                                                const float* __restrict__ w2,
                                                u16* __restrict__ out) {
  const float* W[3] = {w0, w1, w2};
  const int o0t[3] = {1, 0, 0}, o1t[3] = {2, 2, 1};
  const int EE4 = E_DIM * E_DIM / 4;
  const int n4per = 5 * EE4;
  const int total = 3 * n4per;
  int stride = gridDim.x * blockDim.x;
  for (int i = blockIdx.x * blockDim.x + threadIdx.x; i < total; i += stride) {
    int j = (i < n4per) ? 0 : (i < 2 * n4per ? 1 : 2);
    int r = i - j * n4per;
    const float* src;
    if (r < EE4) src = W[j] + 4 * (size_t)r;
    else if (r < 3 * EE4) src = W[o0t[j]] + 4 * (size_t)r;
    else src = W[o1t[j]] + 4 * (size_t)r - 2 * (size_t)E_DIM * E_DIM;
    f32x4 v = *(const f32x4*)src;
    u16x4 o;
    o.x = f2bf(v.x); o.y = f2bf(v.y); o.z = f2bf(v.z); o.w = f2bf(v.w);
    ((u16x4*)out)[(size_t)j * n4per + r] = o;
  }
}

// ---------------- f32 -> bf16 convert, 3 feature buffers in one launch ----------
__global__ __launch_bounds__(256) void cvt3_f32_bf16(const float* __restrict__ i0,
                                                     const float* __restrict__ i1,
                                                     const float* __restrict__ i2,
                                                     u16* __restrict__ o0,
                                                     u16* __restrict__ o1,
                                                     u16* __restrict__ o2, int n4) {
  int stride = gridDim.x * blockDim.x;
  for (int i = blockIdx.x * blockDim.x + threadIdx.x; i < n4; i += stride) {
    f32x4 a = ((const f32x4*)i0)[i];
    f32x4 b = ((const f32x4*)i1)[i];
    f32x4 c = ((const f32x4*)i2)[i];
    u16x4 x, y, z;
    x.x = f2bf(a.x); x.y = f2bf(a.y); x.z = f2bf(a.z); x.w = f2bf(a.w);
    y.x = f2bf(b.x); y.y = f2bf(b.y); y.z = f2bf(b.z); y.w = f2bf(b.w);
    z.x = f2bf(c.x); z.y = f2bf(c.y); z.z = f2bf(c.z); z.w = f2bf(c.w);
    ((u16x4*)o0)[i] = x;
    ((u16x4*)o1)[i] = y;
    ((u16x4*)o2)[i] = z;
  }
}

// ---------------- transpose f32 [n x n] -> bf16 [n x n]^T ----------------
__global__ __launch_bounds__(256) void transpose_to_bf16(const float* __restrict__ in,
                                                         u16* __restrict__ out, int n) {
  __shared__ float t[32][33];
  int bx = blockIdx.x * 32;
  int by = blockIdx.y * 32;
  int tx = threadIdx.x, ty = threadIdx.y;  // 32 x 8
  for (int r = ty; r < 32; r += 8)
    t[r][tx] = in[(size_t)(by + r) * n + bx + tx];
  __syncthreads();
  for (int r = ty; r < 32; r += 8)
    out[(size_t)(bx + r) * n + by + tx] = f2bf(t[tx][r]);
}

// ---------------- folded bias ----------------
__global__ __launch_bounds__(256) void fold_bias(const float* __restrict__ b0,
                                                 const float* __restrict__ b1,
                                                 const float* __restrict__ b2,
                                                 const float* __restrict__ wfuse,
                                                 const float* __restrict__ bfuse,
                                                 float* __restrict__ cb) {
  int wave = threadIdx.x >> 6, lane = threadIdx.x & 63;
  int j = blockIdx.x * 4 + wave;
  const float* wrow = wfuse + (size_t)j * (3 * E_DIM);
  float s = 0.f;
  for (int i = lane; i < E_DIM; i += 64) s += b0[i] * wrow[i];
  for (int i = lane; i < E_DIM; i += 64) s += b1[i] * wrow[E_DIM + i];
  for (int i = lane; i < E_DIM; i += 64) s += b2[i] * wrow[2 * E_DIM + i];
  for (int off = 32; off; off >>= 1) s += __shfl_xor(s, off);
  if (lane == 0) cb[j] = bfuse[j] + s;
}

// ---------------- concat bias, all 3 j in one launch (out stride 5120) --------
__global__ __launch_bounds__(256) void concat_bias3(const float* __restrict__ b0,
                                                    const float* __restrict__ b1,
                                                    const float* __restrict__ b2,
                                                    float* __restrict__ out) {
  const float* B[3] = {b0, b1, b2};
  const int o0t[3] = {1, 0, 0}, o1t[3] = {2, 2, 1};
  int j = blockIdx.x / 20;
  int i = (blockIdx.x % 20) * 256 + threadIdx.x;  // 5120 per j
  float v;
  if (i < 1024) v = B[j][i];
  else if (i < 3072) v = B[o0t[j]][i];
  else v = B[o1t[j]][i - 2048];
  out[(size_t)j * 5120 + i] = v;
}

// ================= GEMM 256x256x64, 8 waves, 4-phase/K-tile =================
// R13: ISSUE-EARLY reads -- ds_reads for phase p+1 are issued BEFORE phase p's
// MFMA cluster; explicit LGKM0/SCHED serializers removed so the compiler emits
// counted lgkmcnt(N) waits and interleaves reads with MFMAs (read latency hides
// under the same phase's MFMA). VMC/BAR/SCHED skeleton + stage order + ledger
// identical to R11 (proven): stage P0:A0' P1:A1' P2:B0' P3:B1';
// waits P0 vmcnt(2) [forces B1(cur)], P3 vmcnt(2) [forces A0',A1',B0'].
// Reads stay on the same side of every barrier as R11; consumers pin them from
// sinking past buffer overwrites (writes to a buffer only issue after the P3
// barrier that every wave reaches only after its reads completed).
#define BM 256
#define BN 256
#define BK 64

#define RDA(buf, qm, dst)                                                         \
  do {                                                                            \
    _Pragma("unroll") for (int m = 0; m < 4; m++)                                 \
    _Pragma("unroll") for (int kk = 0; kk < 2; kk++) {                            \
      int rl = (qm)*64 + m * 16 + l16;                                            \
      int col = ((kk * 64 + kq * 16) ^ ((l16 & 7) << 4)) >> 1;                    \
      dst[m][kk] = *(const bf16x8*)&lds[buf][wm * 8192 + rl * 64 + col];          \
    }                                                                             \
  } while (0)

#define RDB(buf, qn, dst)                                                         \
  do {                                                                            \
    _Pragma("unroll") for (int n = 0; n < 2; n++)                                 \
    _Pragma("unroll") for (int kk = 0; kk < 2; kk++) {                            \
      int rt = (qn)*128 + wn * 32 + n * 16 + l16; /* B half = qn ONLY */          \
      int col = ((kk * 64 + kq * 16) ^ ((l16 & 7) << 4)) >> 1;                    \
      dst[n][kk] = *(const bf16x8*)&lds[buf][16384 + (rt >> 7) * 8192 +           \
                                             (rt & 127) * 64 + col];              \
    }                                                                             \
  } while (0)

#define MMAQ(qm, qn, A_, B_)                                                      \
  do {                                                                            \
    __builtin_amdgcn_s_setprio(1);                                                \
    _Pragma("unroll") for (int m = 0; m < 4; m++)                                 \
    _Pragma("unroll") for (int n = 0; n < 2; n++)                                 \
    _Pragma("unroll") for (int kk = 0; kk < 2; kk++)                              \
      acc[(qm)*4 + m][(qn)*2 + n] = __builtin_amdgcn_mfma_f32_16x16x32_bf16(      \
          A_[m][kk], B_[n][kk], acc[(qm)*4 + m][(qn)*2 + n], 0, 0, 0);            \
    __builtin_amdgcn_s_setprio(0);                                                \
  } while (0)

#define BAR() __builtin_amdgcn_s_barrier()
#define SCHED() __builtin_amdgcn_sched_barrier(0)
#define VMC(n) asm volatile("s_waitcnt vmcnt(" #n ")" ::: "memory")

template <int MODE>
__global__ __launch_bounds__(512, 2) void gemm256(const u16* __restrict__ A,
                                                  const u16* __restrict__ W,
                                                  void* __restrict__ Cp,
                                                  const float* __restrict__ bias,
                                                  int lda, int ldw, int ldc, int K,
                                                  int nbn, int njb,
                                                  long jsA, long jsW, long jsC, long jsB) {
  __shared__ __align__(16) u16 lds[2][32768];  // 128 KB

  const int tid = threadIdx.x;
  const int wave = tid >> 6;
  const int lane = tid & 63;
  const int wm = wave >> 2;   // 0..1: 128-row half (reads A half wm only)
  const int wn = wave & 3;    // 0..3: 32-col subgroup within each B half
  const int l16 = lane & 15;
  const int kq = lane >> 4;

  // T1: bijective XCD-aware block swizzle (static grid -> locality preserved)
  const int nwg = gridDim.x;
  int bid = blockIdx.x;
  int xcd = bid & 7, orig = bid >> 3;
  int q8 = nwg >> 3, r8 = nwg & 7;
  int wg = (xcd < r8 ? xcd * (q8 + 1) : r8 * (q8 + 1) + (xcd - r8) * q8) + orig;
  const int j = wg / njb;
  const int rem = wg - j * njb;
  const int bm = rem / nbn;
  const int bn = rem % nbn;

  const u16* Ab = A + j * jsA + (size_t)bm * BM * lda;
  const u16* Wb = W + j * jsW + (size_t)bn * BN * ldw;

  f32x4 acc[8][4];
#pragma unroll
  for (int i = 0; i < 8; i++)
#pragma unroll
    for (int n = 0; n < 4; n++) acc[i][n] = (f32x4){0.f, 0.f, 0.f, 0.f};

  // stage one half-tile: 0=A0,1=A1,2=B0,3=B1 (base = which*8192 el)
  auto stageH = [&](int buf, int which, int k0) {
    const u16* src = (which >= 2) ? Wb : Ab;
    const int ld = (which >= 2) ? ldw : lda;
    const int h = which & 1;
#pragma unroll
    for (int r = 0; r < 2; r++) {
      int slot = r * 512 + tid;               // 1024 slots = 128 rows x 8 chunks
      int row = h * 128 + (slot >> 3);
      int col = ((slot & 7) ^ (row & 7)) * 8; // pre-swizzled source (involution)
      gload16(src + (size_t)row * ld + k0 + col, &lds[buf][which * 8192 + slot * 8]);
    }
  };

  const int nt = K / BK;

  // prologue: stage A0,A1,B0,B1; vmcnt(2) forces A0,A1,B0; pre-read a0,b0
  stageH(0, 0, 0); stageH(0, 1, 0); stageH(0, 2, 0); stageH(0, 3, 0);
  VMC(2);
  BAR();
  SCHED();

  bf16x8 a0[4][2], a1[4][2], b0[2][2], b1[2][2];
  RDA(0, 0, a0);
  RDB(0, 0, b0);

  int cur = 0;
  for (int t = 0; t < nt; ++t) {
    const bool pf = (t + 1 < nt);
    const int nb = cur ^ 1;
    const int nk = (t + 1) * BK;
    // ---- P0: stage A0'; force B1(cur); issue b1 reads; MFMA Q(0,0) ----
    if (pf) stageH(nb, 0, nk);
    if (pf) VMC(2); else VMC(0);
    BAR();
    SCHED();
    RDB(cur, 1, b1);              // consumed P1; hides under P0 MFMA
    MMAQ(0, 0, a0, b0);
    // ---- P1: stage A1'; issue a1 reads; MFMA Q(0,1) ----
    if (pf) stageH(nb, 1, nk);
    RDA(cur, 1, a1);              // consumed P2; hides under P1 MFMA
    MMAQ(0, 1, a0, b1);
    // ---- P2: stage B0'; MFMA Q(1,0) ----
    if (pf) stageH(nb, 2, nk);
    MMAQ(1, 0, a1, b0);
    // ---- P3: stage B1'; force A0',A1',B0'; issue a0',b0' reads; MFMA Q(1,1) ----
    if (pf) {
      stageH(nb, 3, nk);
      VMC(2);
      BAR();
      SCHED();
      RDA(nb, 0, a0);             // consumed next P0; hides under P3 MFMA
      RDB(nb, 0, b0);
    }
    MMAQ(1, 1, a1, b1);
    cur ^= 1;
  }

  const int r0 = kq * 4;  // C/D: col = lane&15, row = (lane>>4)*4 + r
#pragma unroll
  for (int mf = 0; mf < 8; mf++) {
#pragma unroll
    for (int nf = 0; nf < 4; nf++) {
      int row = bm * BM + wm * 128 + mf * 16 + r0;
      int col = bn * BN + (nf >> 1) * 128 + wn * 32 + (nf & 1) * 16 + l16;
      if (MODE == 0) {
        u16* C = (u16*)Cp + j * jsC;
        float bv = bias ? bias[j * jsB + col] : 0.f;
#pragma unroll
        for (int r = 0; r < 4; r++)
          C[(size_t)(row + r) * ldc + col] = f2bf(acc[mf][nf][r] + bv);
      } else {
        float* C = (float*)Cp + j * jsC;
        float bv = bias[j * jsB + col];
#pragma unroll
        for (int r = 0; r < 4; r++)
          C[(size_t)(row + r) * ldc + col] = acc[mf][nf][r] + bv;
      }
    }
  }
}

// ---------------- attention combine: all 3 MHAs, VECTORIZED (bf16x8/lane) -----
__global__ __launch_bounds__(256) void attn_combine3(const u16* __restrict__ Pb,
                                                     long jsP, u16* __restrict__ Oc) {
  int grp = blockIdx.x * 32 + (threadIdx.x >> 3);  // (b,h) group
  int l8 = threadIdx.x & 7;
  int b = grp >> 4, h = grp & 15;
  size_t prow = (size_t)b * 5120;
  int dbase = h * 64 + l8 * 8;
  const int j1a[3] = {1, 0, 0}, j2a[3] = {2, 2, 1};
  const int offA[3] = {1024, 1024, 3072}, offB[3] = {1024, 3072, 3072};
#pragma unroll
  for (int m = 0; m < 3; m++) {
    const u16* Pq = Pb + m * jsP;
    const u16* Pa = Pb + j1a[m] * jsP;
    const u16* Pc = Pb + j2a[m] * jsP;
    bf16x8 qv = *(const bf16x8*)&Pq[prow + dbase];
    bf16x8 k1 = *(const bf16x8*)&Pa[prow + offA[m] + dbase];
    bf16x8 v1 = *(const bf16x8*)&Pa[prow + offA[m] + 1024 + dbase];
    bf16x8 k2 = *(const bf16x8*)&Pc[prow + offB[m] + dbase];
    bf16x8 v2 = *(const bf16x8*)&Pc[prow + offB[m] + 1024 + dbase];
    float s1 = 0.f, s2 = 0.f;
#pragma unroll
    for (int e = 0; e < 8; e++) {
      float q = bf2f((u16)qv[e]);
      s1 += q * bf2f((u16)k1[e]);
      s2 += q * bf2f((u16)k2[e]);
    }
    s1 += __shfl_xor(s1, 1); s1 += __shfl_xor(s1, 2); s1 += __shfl_xor(s1, 4);
    s2 += __shfl_xor(s2, 1); s2 += __shfl_xor(s2, 2); s2 += __shfl_xor(s2, 4);
    s1 *= 0.125f; s2 *= 0.125f;  // 1/sqrt(64)
    float mx = fmaxf(s1, s2);
    float e1 = __expf(s1 - mx), e2 = __expf(s2 - mx);
    float rn = 1.f / (e1 + e2);
    float w1 = e1 * rn, w2 = e2 * rn;
    bf16x8 ov;
#pragma unroll
    for (int e = 0; e < 8; e++)
      ov[e] = (short)f2bf(w1 * bf2f((u16)v1[e]) + w2 * bf2f((u16)v2[e]));
    *(bf16x8*)&Oc[(size_t)b * 3072 + m * 1024 + dbase] = ov;
  }
}

// ---------------- layernorm in place on f32 [B,1024] ----------------
__global__ __launch_bounds__(256) void layernorm_inplace(float* __restrict__ y,
                                                         const float* __restrict__ g,
                                                         const float* __restrict__ b) {
  int row = blockIdx.x, tid = threadIdx.x;
  float* yr = y + (size_t)row * E_DIM;
  f32x4 v = ((const f32x4*)yr)[tid];
  float s = v.x + v.y + v.z + v.w;
  float sq = v.x * v.x + v.y * v.y + v.z * v.z + v.w * v.w;
  for (int off = 32; off; off >>= 1) {
    s += __shfl_xor(s, off);
    sq += __shfl_xor(sq, off);
  }
  __shared__ float rs[4], rq[4];
  int wave = tid >> 6, lane = tid & 63;
  if (lane == 0) { rs[wave] = s; rq[wave] = sq; }
  __syncthreads();
  s = rs[0] + rs[1] + rs[2] + rs[3];
  sq = rq[0] + rq[1] + rq[2] + rq[3];
  float mu = s * (1.f / E_DIM);
  float var = sq * (1.f / E_DIM) - mu * mu;
  float rstd = rsqrtf(var + 1e-5f);
  f32x4 gg = ((const f32x4*)g)[tid];
  f32x4 bb = ((const f32x4*)b)[tid];
  f32x4 o;
  o.x = (v.x - mu) * rstd * gg.x + bb.x;
  o.y = (v.y - mu) * rstd * gg.y + bb.y;
  o.z = (v.z - mu) * rstd * gg.z + bb.z;
  o.w = (v.w - mu) * rstd * gg.w + bb.w;
  ((f32x4*)yr)[tid] = o;
}

extern "C" void kernel_launch(void* const* d_in, const int* in_sizes, int n_in,
                              void* d_out, int out_size, void* d_ws, size_t ws_size,
                              hipStream_t stream) {
  const float* feat[3] = {(const float*)d_in[0], (const float*)d_in[1], (const float*)d_in[2]};
  const float* w_in[3] = {(const float*)d_in[3], (const float*)d_in[7], (const float*)d_in[11]};
  const float* b_in[3] = {(const float*)d_in[4], (const float*)d_in[8], (const float*)d_in[12]};
  const float* w_out[3] = {(const float*)d_in[5], (const float*)d_in[9], (const float*)d_in[13]};
  const float* b_out[3] = {(const float*)d_in[6], (const float*)d_in[10], (const float*)d_in[14]};
  const float* w_fuse = (const float*)d_in[15];
  const float* b_fuse = (const float*)d_in[16];
  const float* ln_g = (const float*)d_in[17];
  const float* ln_b = (const float*)d_in[18];

  auto A256 = [](size_t b) { return (b + 255) & ~(size_t)255; };
  const size_t EE = (size_t)E_DIM * E_DIM;

  const size_t persist = 3 * A256(5 * EE * 2) + 3 * A256(5 * E_DIM * 4) +
                         A256(3 * EE * 2) + A256(E_DIM * 4);

  // Preferred: CH=2048 chunks for proj/combine + FULL Ocat (one final GEMM).
  int CH = 2048;
  bool bigOcat;
  {
    size_t need = persist + 3 * A256((size_t)CH * E_DIM * 2) +
                  3 * A256((size_t)CH * 5 * E_DIM * 2) +
                  A256((size_t)B_ROWS * 3 * E_DIM * 2);
    bigOcat = (need <= ws_size);
  }
  if (!bigOcat) {
    CH = B_ROWS;
    while (CH > 256) {
      size_t pool = 3 * A256((size_t)CH * E_DIM * 2) + 3 * A256((size_t)CH * 5 * E_DIM * 2) +
                    A256((size_t)CH * 3 * E_DIM * 2);
      if (persist + pool <= ws_size) break;
      CH -= 256;
    }
  }

  char* p = (char*)d_ws;
  auto alloc = [&](size_t bytes) {
    void* r = (void*)p;
    p += A256(bytes);
    return r;
  };

  u16* Wcat[3];
  for (int i = 0; i < 3; i++) Wcat[i] = (u16*)alloc(5 * EE * 2);   // contiguous, stride 5EE
  float* bcat[3];
  for (int i = 0; i < 3; i++) bcat[i] = (float*)alloc(5 * E_DIM * 4);  // contiguous, stride 5120
  u16* Mcat = (u16*)alloc(3 * EE * 2);
  float* cb = (float*)alloc(E_DIM * 4);

  char* pool = p;

  // ---- stage 0: all Wcat in ONE launch + all bcat in ONE launch ----
  cvt_wcat<<<2048, 256, 0, stream>>>(w_in[0], w_in[1], w_in[2], Wcat[0]);
  concat_bias3<<<60, 256, 0, stream>>>(b_in[0], b_in[1], b_in[2], bcat[0]);

  // ---- stage 1: Mcat slices (ONE batched GEMM over f) + folded bias ----
  {
    u16* wfusebf = (u16*)pool;
    u16* woutT0 = (u16*)(pool + A256(3 * EE * 2));
    const long jsWT = (long)(A256(EE * 2) / 2);  // woutT stride (elements)
    cvt_f32_bf16<<<1024, 256, 0, stream>>>(w_fuse, wfusebf, (int)(3 * EE / 4));
    dim3 tb(32, 8);
    for (int f = 0; f < 3; f++)
      transpose_to_bf16<<<dim3(E_DIM / 32, E_DIM / 32), tb, 0, stream>>>(
          w_out[f], woutT0 + f * jsWT, E_DIM);
    // batched over f: Mcat[:, f*E:(f+1)E] = w_fuse[:, fE:(f+1)E] @ w_out_f
    gemm256<0><<<48, 512, 0, stream>>>(
        wfusebf, woutT0, (void*)Mcat, nullptr,
        3 * E_DIM, E_DIM, 3 * E_DIM, E_DIM, E_DIM / BN, 16,
        (long)E_DIM, jsWT, (long)E_DIM, 0);
    fold_bias<<<E_DIM / 4, 256, 0, stream>>>(b_out[0], b_out[1], b_out[2], w_fuse, b_fuse, cb);
  }

  // ---- stage 2: chunk loop ----
  {
    char* q = pool;
    auto palloc = [&](size_t bytes) {
      void* r = (void*)q;
      q += A256(bytes);
      return r;
    };
    u16* fb0 = (u16*)palloc(3 * A256((size_t)CH * E_DIM * 2));
    u16* P0 = (u16*)palloc(3 * A256((size_t)CH * 5 * E_DIM * 2));
    u16* Ocat = (u16*)palloc(bigOcat ? (size_t)B_ROWS * 3 * E_DIM * 2
                                     : (size_t)CH * 3 * E_DIM * 2);
    const long jsA = (long)CH * E_DIM;            // fb stride (elements)
    const long jsP = (long)CH * 5 * E_DIM;        // P stride (elements)
    const long jsW = (long)(A256(5 * EE * 2) / 2);
    const long jsB = 5 * E_DIM;

    for (int row0 = 0; row0 < B_ROWS; row0 += CH) {
      int rows = B_ROWS - row0 < CH ? B_ROWS - row0 : CH;
      cvt3_f32_bf16<<<1024, 256, 0, stream>>>(
          feat[0] + (size_t)row0 * E_DIM, feat[1] + (size_t)row0 * E_DIM,
          feat[2] + (size_t)row0 * E_DIM, fb0, fb0 + jsA, fb0 + 2 * jsA,
          rows * (E_DIM / 4));
      // merged projection: P[j] = fb[j] @ Wcat_j^T + bcat_j   [rows, 5120]
      const int njb = (rows / BM) * (5 * E_DIM / BN);
      gemm256<0><<<3 * njb, 512, 0, stream>>>(
          fb0, Wcat[0], (void*)P0, bcat[0], E_DIM, E_DIM, 5 * E_DIM, E_DIM,
          5 * E_DIM / BN, njb, jsA, jsW, jsP, jsB);
      // softmax-combine (all 3 MHAs, vectorized) into Ocat rows [row0, row0+rows)
      u16* Oc = bigOcat ? Ocat + (size_t)row0 * 3 * E_DIM : Ocat;
      attn_combine3<<<rows * H_N / 32, 256, 0, stream>>>(P0, jsP, Oc);
      if (!bigOcat) {
        int nt2 = (rows / BM) * (E_DIM / BN);
        gemm256<1><<<nt2, 512, 0, stream>>>(
            Ocat, Mcat, (void*)((float*)d_out + (size_t)row0 * E_DIM), cb,
            3 * E_DIM, 3 * E_DIM, E_DIM, 3 * E_DIM, E_DIM / BN, nt2, 0, 0, 0, 0);
      }
    }
    if (bigOcat) {
      int nt2 = (B_ROWS / BM) * (E_DIM / BN);  // 256 = exactly one machine round
      gemm256<1><<<nt2, 512, 0, stream>>>(
          Ocat, Mcat, d_out, cb, 3 * E_DIM, 3 * E_DIM, E_DIM, 3 * E_DIM,
          E_DIM / BN, nt2, 0, 0, 0, 0);
    }
  }

  // ---- stage 3: layernorm in place on d_out ----
  layernorm_inplace<<<B_ROWS, 256, 0, stream>>>((float*)d_out, ln_g, ln_b);
}

// Round 15
// 912.012 us; speedup vs baseline: 1.2393x; 1.2393x over previous
//
#include <hip/hip_runtime.h>
#include <stdint.h>

#define B_ROWS 16384
#define E_DIM 1024
#define H_N 16

typedef unsigned short u16;
typedef __attribute__((ext_vector_type(4))) float f32x4;
typedef __attribute__((ext_vector_type(4))) unsigned short u16x4;
typedef __attribute__((ext_vector_type(8))) short bf16x8;

static __device__ __forceinline__ u16 f2bf(float f) {
  union { float f; unsigned u; } x; x.f = f;
  unsigned r = (x.u + 0x7FFFu + ((x.u >> 16) & 1u)) >> 16;
  return (u16)r;
}
static __device__ __forceinline__ float bf2f(u16 h) {
  union { unsigned u; float f; } x; x.u = ((unsigned)h) << 16;
  return x.f;
}

typedef const __attribute__((address_space(1))) void gvoid;
typedef __attribute__((address_space(3))) void lvoid;
static __device__ __forceinline__ void gload16(const void* g, void* l) {
  __builtin_amdgcn_global_load_lds((gvoid*)g, (lvoid*)l, 16, 0, 0);
}

// ---------------- f32 -> bf16 convert (single buffer) ----------------
__global__ __launch_bounds__(256) void cvt_f32_bf16(const float* __restrict__ in,
                                                    u16* __restrict__ out, int n4) {
  int stride = gridDim.x * blockDim.x;
  for (int i = blockIdx.x * blockDim.x + threadIdx.x; i < n4; i += stride) {
    f32x4 v = ((const f32x4*)in)[i];
    u16x4 o;
    o.x = f2bf(v.x); o.y = f2bf(v.y); o.z = f2bf(v.z); o.w = f2bf(v.w);
    ((u16x4*)out)[i] = o;
  }
}

// ---------------- build ALL THREE Wcat_j = [wq_j ; wkv_o0 ; wkv_o1] in one launch
__global__ __launch_bounds__(256) void cvt_wcat(const float* __restrict__ w0,
                                                const float* __restrict__ w1,
                                                const float* __restrict__ w2,
                                                u16* __restrict__ out) {
  const float* W[3] = {w0, w1, w2};
  const int o0t[3] = {1, 0, 0}, o1t[3] = {2, 2, 1};
  const int EE4 = E_DIM * E_DIM / 4;
  const int n4per = 5 * EE4;
  const int total = 3 * n4per;
  int stride = gridDim.x * blockDim.x;
  for (int i = blockIdx.x * blockDim.x + threadIdx.x; i < total; i += stride) {
    int j = (i < n4per) ? 0 : (i < 2 * n4per ? 1 : 2);
    int r = i - j * n4per;
    const float* src;
    if (r < EE4) src = W[j] + 4 * (size_t)r;
    else if (r < 3 * EE4) src = W[o0t[j]] + 4 * (size_t)r;
    else src = W[o1t[j]] + 4 * (size_t)r - 2 * (size_t)E_DIM * E_DIM;
    f32x4 v = *(const f32x4*)src;
    u16x4 o;
    o.x = f2bf(v.x); o.y = f2bf(v.y); o.z = f2bf(v.z); o.w = f2bf(v.w);
    ((u16x4*)out)[(size_t)j * n4per + r] = o;
  }
}

// ---------------- f32 -> bf16 convert, 3 feature buffers in one launch ----------
__global__ __launch_bounds__(256) void cvt3_f32_bf16(const float* __restrict__ i0,
                                                     const float* __restrict__ i1,
                                                     const float* __restrict__ i2,
                                                     u16* __restrict__ o0,
                                                     u16* __restrict__ o1,
                                                     u16* __restrict__ o2, int n4) {
  int stride = gridDim.x * blockDim.x;
  for (int i = blockIdx.x * blockDim.x + threadIdx.x; i < n4; i += stride) {
    f32x4 a = ((const f32x4*)i0)[i];
    f32x4 b = ((const f32x4*)i1)[i];
    f32x4 c = ((const f32x4*)i2)[i];
    u16x4 x, y, z;
    x.x = f2bf(a.x); x.y = f2bf(a.y); x.z = f2bf(a.z); x.w = f2bf(a.w);
    y.x = f2bf(b.x); y.y = f2bf(b.y); y.z = f2bf(b.z); y.w = f2bf(b.w);
    z.x = f2bf(c.x); z.y = f2bf(c.y); z.z = f2bf(c.z); z.w = f2bf(c.w);
    ((u16x4*)o0)[i] = x;
    ((u16x4*)o1)[i] = y;
    ((u16x4*)o2)[i] = z;
  }
}

// ---------------- transpose f32 [n x n] -> bf16 [n x n]^T ----------------
__global__ __launch_bounds__(256) void transpose_to_bf16(const float* __restrict__ in,
                                                         u16* __restrict__ out, int n) {
  __shared__ float t[32][33];
  int bx = blockIdx.x * 32;
  int by = blockIdx.y * 32;
  int tx = threadIdx.x, ty = threadIdx.y;  // 32 x 8
  for (int r = ty; r < 32; r += 8)
    t[r][tx] = in[(size_t)(by + r) * n + bx + tx];
  __syncthreads();
  for (int r = ty; r < 32; r += 8)
    out[(size_t)(bx + r) * n + by + tx] = f2bf(t[tx][r]);
}

// ---------------- folded bias ----------------
__global__ __launch_bounds__(256) void fold_bias(const float* __restrict__ b0,
                                                 const float* __restrict__ b1,
                                                 const float* __restrict__ b2,
                                                 const float* __restrict__ wfuse,
                                                 const float* __restrict__ bfuse,
                                                 float* __restrict__ cb) {
  int wave = threadIdx.x >> 6, lane = threadIdx.x & 63;
  int j = blockIdx.x * 4 + wave;
  const float* wrow = wfuse + (size_t)j * (3 * E_DIM);
  float s = 0.f;
  for (int i = lane; i < E_DIM; i += 64) s += b0[i] * wrow[i];
  for (int i = lane; i < E_DIM; i += 64) s += b1[i] * wrow[E_DIM + i];
  for (int i = lane; i < E_DIM; i += 64) s += b2[i] * wrow[2 * E_DIM + i];
  for (int off = 32; off; off >>= 1) s += __shfl_xor(s, off);
  if (lane == 0) cb[j] = bfuse[j] + s;
}

// ---------------- concat bias, all 3 j in one launch (out stride 5120) --------
__global__ __launch_bounds__(256) void concat_bias3(const float* __restrict__ b0,
                                                    const float* __restrict__ b1,
                                                    const float* __restrict__ b2,
                                                    float* __restrict__ out) {
  const float* B[3] = {b0, b1, b2};
  const int o0t[3] = {1, 0, 0}, o1t[3] = {2, 2, 1};
  int j = blockIdx.x / 20;
  int i = (blockIdx.x % 20) * 256 + threadIdx.x;  // 5120 per j
  float v;
  if (i < 1024) v = B[j][i];
  else if (i < 3072) v = B[o0t[j]][i];
  else v = B[o1t[j]][i - 2048];
  out[(size_t)j * 5120 + i] = v;
}

// ================= GEMM 256x256x64, 8 waves, 4-phase/K-tile =================
// R15 = R14 with the A-half race fixed (R10 lesson re-applied):
// RDA(buf,·) reads the wave's OWN A half (wm) -> any pre-read of a new buffer's
// "a0" touches BOTH A halves; every wait that precedes such a read must force
// BOTH A stages. Hence prologue and P3 use vmcnt(2) (NOT 4): only the newest
// B1-stage may float across those waits, and B1 is forced by P0's vmcnt(4)
// before its first read.
// Stage (buffer nb during iter t): P0:{A0',B0'} P1:{A1',B1'} P2/P3: none.
// Ledger (2 loads/stageH; in-order-oldest vmcnt):
//   prologue: stage[A0,B0,A1,B1](8) -> vmcnt(2) forces A0,B0,A1 -> BAR ->
//             pre-read a0 (A0+A1 ok), b0 (B0 ok); B1 floats.
//   P0: stage A0'',B0'' -> outst {B1',A0'',B0''}=6 -> MMAQ Q00 -> vmcnt(4)
//       forces B1' -> BAR -> read b1.
//   P1: stage A1'',B1'' (outst 8) -> MMAQ Q01 -> read a1 (A0',A1' forced prior).
//   P2: MMAQ Q10.
//   P3: MMAQ Q11 -> vmcnt(2) forces A0'',B0'',A1'' -> BAR -> read a0,b0 of nb.
//   Tails: P0 vmcnt(0); P3 pf-gated.
// LGKM0+SCHED retained at each phase entry before MFMA (R13: removing = -40%).
#define BM 256
#define BN 256
#define BK 64

#define RDA(buf, qm, dst)                                                         \
  do {                                                                            \
    _Pragma("unroll") for (int m = 0; m < 4; m++)                                 \
    _Pragma("unroll") for (int kk = 0; kk < 2; kk++) {                            \
      int rl = (qm)*64 + m * 16 + l16;                                            \
      int col = ((kk * 64 + kq * 16) ^ ((l16 & 7) << 4)) >> 1;                    \
      dst[m][kk] = *(const bf16x8*)&lds[buf][wm * 8192 + rl * 64 + col];          \
    }                                                                             \
  } while (0)

#define RDB(buf, qn, dst)                                                         \
  do {                                                                            \
    _Pragma("unroll") for (int n = 0; n < 2; n++)                                 \
    _Pragma("unroll") for (int kk = 0; kk < 2; kk++) {                            \
      int rt = (qn)*128 + wn * 32 + n * 16 + l16; /* B half = qn ONLY */          \
      int col = ((kk * 64 + kq * 16) ^ ((l16 & 7) << 4)) >> 1;                    \
      dst[n][kk] = *(const bf16x8*)&lds[buf][16384 + (rt >> 7) * 8192 +           \
                                             (rt & 127) * 64 + col];              \
    }                                                                             \
  } while (0)

#define MMAQ(qm, qn, A_, B_)                                                      \
  do {                                                                            \
    __builtin_amdgcn_s_setprio(1);                                                \
    _Pragma("unroll") for (int m = 0; m < 4; m++)                                 \
    _Pragma("unroll") for (int n = 0; n < 2; n++)                                 \
    _Pragma("unroll") for (int kk = 0; kk < 2; kk++)                              \
      acc[(qm)*4 + m][(qn)*2 + n] = __builtin_amdgcn_mfma_f32_16x16x32_bf16(      \
          A_[m][kk], B_[n][kk], acc[(qm)*4 + m][(qn)*2 + n], 0, 0, 0);            \
    __builtin_amdgcn_s_setprio(0);                                                \
  } while (0)

#define BAR() __builtin_amdgcn_s_barrier()
#define SCHED() __builtin_amdgcn_sched_barrier(0)
#define LGKM0() asm volatile("s_waitcnt lgkmcnt(0)" ::: "memory")
#define VMC(n) asm volatile("s_waitcnt vmcnt(" #n ")" ::: "memory")

template <int MODE>
__global__ __launch_bounds__(512, 2) void gemm256(const u16* __restrict__ A,
                                                  const u16* __restrict__ W,
                                                  void* __restrict__ Cp,
                                                  const float* __restrict__ bias,
                                                  int lda, int ldw, int ldc, int K,
                                                  int nbn, int njb,
                                                  long jsA, long jsW, long jsC, long jsB) {
  __shared__ __align__(16) u16 lds[2][32768];  // 128 KB

  const int tid = threadIdx.x;
  const int wave = tid >> 6;
  const int lane = tid & 63;
  const int wm = wave >> 2;   // 0..1: 128-row half (reads A half wm only)
  const int wn = wave & 3;    // 0..3: 32-col subgroup within each B half
  const int l16 = lane & 15;
  const int kq = lane >> 4;

  // T1: bijective XCD-aware block swizzle (static grid -> locality preserved)
  const int nwg = gridDim.x;
  int bid = blockIdx.x;
  int xcd = bid & 7, orig = bid >> 3;
  int q8 = nwg >> 3, r8 = nwg & 7;
  int wg = (xcd < r8 ? xcd * (q8 + 1) : r8 * (q8 + 1) + (xcd - r8) * q8) + orig;
  const int j = wg / njb;
  const int rem = wg - j * njb;
  const int bm = rem / nbn;
  const int bn = rem % nbn;

  const u16* Ab = A + j * jsA + (size_t)bm * BM * lda;
  const u16* Wb = W + j * jsW + (size_t)bn * BN * ldw;

  f32x4 acc[8][4];
#pragma unroll
  for (int i = 0; i < 8; i++)
#pragma unroll
    for (int n = 0; n < 4; n++) acc[i][n] = (f32x4){0.f, 0.f, 0.f, 0.f};

  // stage one half-tile: 0=A0,1=A1,2=B0,3=B1 (base = which*8192 el)
  auto stageH = [&](int buf, int which, int k0) {
    const u16* src = (which >= 2) ? Wb : Ab;
    const int ld = (which >= 2) ? ldw : lda;
    const int h = which & 1;
#pragma unroll
    for (int r = 0; r < 2; r++) {
      int slot = r * 512 + tid;               // 1024 slots = 128 rows x 8 chunks
      int row = h * 128 + (slot >> 3);
      int col = ((slot & 7) ^ (row & 7)) * 8; // pre-swizzled source (involution)
      gload16(src + (size_t)row * ld + k0 + col, &lds[buf][which * 8192 + slot * 8]);
    }
  };

  const int nt = K / BK;

  // prologue: stage [A0,B0,A1,B1]; vmcnt(2) forces A0,B0,A1 (B1 floats);
  // pre-read a0 (touches A0+A1 per wm), b0.
  stageH(0, 0, 0); stageH(0, 2, 0); stageH(0, 1, 0); stageH(0, 3, 0);
  VMC(2);
  BAR();
  SCHED();

  bf16x8 a0[4][2], a1[4][2], b0[2][2], b1[2][2];
  RDA(0, 0, a0);
  RDB(0, 0, b0);

  int cur = 0;
  for (int t = 0; t < nt; ++t) {
    const bool pf = (t + 1 < nt);
    const int nb = cur ^ 1;
    const int nk = (t + 1) * BK;
    // ---- P0: stage A0',B0'; MFMA Q(0,0); then force B1(cur); read b1 ----
    if (pf) { stageH(nb, 0, nk); stageH(nb, 2, nk); }
    LGKM0();
    SCHED();
    MMAQ(0, 0, a0, b0);
    if (pf) VMC(4); else VMC(0);   // forces B1(cur) [staged P1(t-1): 3-ph lead]
    BAR();
    SCHED();
    RDB(cur, 1, b1);
    // ---- P1: stage A1',B1'; MFMA Q(0,1); read a1(cur) (A fully forced) ----
    if (pf) { stageH(nb, 1, nk); stageH(nb, 3, nk); }
    LGKM0();
    SCHED();
    MMAQ(0, 1, a0, b1);
    RDA(cur, 1, a1);
    // ---- P2: MFMA Q(1,0) ----
    LGKM0();
    SCHED();
    MMAQ(1, 0, a1, b0);
    // ---- P3: MFMA Q(1,1); then force A0',B0',A1'; read a0',b0' (next buf) ----
    LGKM0();
    SCHED();
    MMAQ(1, 1, a1, b1);
    if (pf) {
      VMC(2);                      // forces A0',B0',A1' (B1' floats to next P0)
      BAR();
      SCHED();
      RDA(nb, 0, a0);              // touches A0'+A1' per wm -- both forced
      RDB(nb, 0, b0);
    }
    cur ^= 1;
  }

  const int r0 = kq * 4;  // C/D: col = lane&15, row = (lane>>4)*4 + r
#pragma unroll
  for (int mf = 0; mf < 8; mf++) {
#pragma unroll
    for (int nf = 0; nf < 4; nf++) {
      int row = bm * BM + wm * 128 + mf * 16 + r0;
      int col = bn * BN + (nf >> 1) * 128 + wn * 32 + (nf & 1) * 16 + l16;
      if (MODE == 0) {
        u16* C = (u16*)Cp + j * jsC;
        float bv = bias ? bias[j * jsB + col] : 0.f;
#pragma unroll
        for (int r = 0; r < 4; r++)
          C[(size_t)(row + r) * ldc + col] = f2bf(acc[mf][nf][r] + bv);
      } else {
        float* C = (float*)Cp + j * jsC;
        float bv = bias[j * jsB + col];
#pragma unroll
        for (int r = 0; r < 4; r++)
          C[(size_t)(row + r) * ldc + col] = acc[mf][nf][r] + bv;
      }
    }
  }
}

// ---------------- attention combine: all 3 MHAs, VECTORIZED (bf16x8/lane) -----
__global__ __launch_bounds__(256) void attn_combine3(const u16* __restrict__ Pb,
                                                     long jsP, u16* __restrict__ Oc) {
  int grp = blockIdx.x * 32 + (threadIdx.x >> 3);  // (b,h) group
  int l8 = threadIdx.x & 7;
  int b = grp >> 4, h = grp & 15;
  size_t prow = (size_t)b * 5120;
  int dbase = h * 64 + l8 * 8;
  const int j1a[3] = {1, 0, 0}, j2a[3] = {2, 2, 1};
  const int offA[3] = {1024, 1024, 3072}, offB[3] = {1024, 3072, 3072};
#pragma unroll
  for (int m = 0; m < 3; m++) {
    const u16* Pq = Pb + m * jsP;
    const u16* Pa = Pb + j1a[m] * jsP;
    const u16* Pc = Pb + j2a[m] * jsP;
    bf16x8 qv = *(const bf16x8*)&Pq[prow + dbase];
    bf16x8 k1 = *(const bf16x8*)&Pa[prow + offA[m] + dbase];
    bf16x8 v1 = *(const bf16x8*)&Pa[prow + offA[m] + 1024 + dbase];
    bf16x8 k2 = *(const bf16x8*)&Pc[prow + offB[m] + dbase];
    bf16x8 v2 = *(const bf16x8*)&Pc[prow + offB[m] + 1024 + dbase];
    float s1 = 0.f, s2 = 0.f;
#pragma unroll
    for (int e = 0; e < 8; e++) {
      float q = bf2f((u16)qv[e]);
      s1 += q * bf2f((u16)k1[e]);
      s2 += q * bf2f((u16)k2[e]);
    }
    s1 += __shfl_xor(s1, 1); s1 += __shfl_xor(s1, 2); s1 += __shfl_xor(s1, 4);
    s2 += __shfl_xor(s2, 1); s2 += __shfl_xor(s2, 2); s2 += __shfl_xor(s2, 4);
    s1 *= 0.125f; s2 *= 0.125f;  // 1/sqrt(64)
    float mx = fmaxf(s1, s2);
    float e1 = __expf(s1 - mx), e2 = __expf(s2 - mx);
    float rn = 1.f / (e1 + e2);
    float w1 = e1 * rn, w2 = e2 * rn;
    bf16x8 ov;
#pragma unroll
    for (int e = 0; e < 8; e++)
      ov[e] = (short)f2bf(w1 * bf2f((u16)v1[e]) + w2 * bf2f((u16)v2[e]));
    *(bf16x8*)&Oc[(size_t)b * 3072 + m * 1024 + dbase] = ov;
  }
}

// ---------------- layernorm in place on f32 [B,1024] ----------------
__global__ __launch_bounds__(256) void layernorm_inplace(float* __restrict__ y,
                                                         const float* __restrict__ g,
                                                         const float* __restrict__ b) {
  int row = blockIdx.x, tid = threadIdx.x;
  float* yr = y + (size_t)row * E_DIM;
  f32x4 v = ((const f32x4*)yr)[tid];
  float s = v.x + v.y + v.z + v.w;
  float sq = v.x * v.x + v.y * v.y + v.z * v.z + v.w * v.w;
  for (int off = 32; off; off >>= 1) {
    s += __shfl_xor(s, off);
    sq += __shfl_xor(sq, off);
  }
  __shared__ float rs[4], rq[4];
  int wave = tid >> 6, lane = tid & 63;
  if (lane == 0) { rs[wave] = s; rq[wave] = sq; }
  __syncthreads();
  s = rs[0] + rs[1] + rs[2] + rs[3];
  sq = rq[0] + rq[1] + rq[2] + rq[3];
  float mu = s * (1.f / E_DIM);
  float var = sq * (1.f / E_DIM) - mu * mu;
  float rstd = rsqrtf(var + 1e-5f);
  f32x4 gg = ((const f32x4*)g)[tid];
  f32x4 bb = ((const f32x4*)b)[tid];
  f32x4 o;
  o.x = (v.x - mu) * rstd * gg.x + bb.x;
  o.y = (v.y - mu) * rstd * gg.y + bb.y;
  o.z = (v.z - mu) * rstd * gg.z + bb.z;
  o.w = (v.w - mu) * rstd * gg.w + bb.w;
  ((f32x4*)yr)[tid] = o;
}

extern "C" void kernel_launch(void* const* d_in, const int* in_sizes, int n_in,
                              void* d_out, int out_size, void* d_ws, size_t ws_size,
                              hipStream_t stream) {
  const float* feat[3] = {(const float*)d_in[0], (const float*)d_in[1], (const float*)d_in[2]};
  const float* w_in[3] = {(const float*)d_in[3], (const float*)d_in[7], (const float*)d_in[11]};
  const float* b_in[3] = {(const float*)d_in[4], (const float*)d_in[8], (const float*)d_in[12]};
  const float* w_out[3] = {(const float*)d_in[5], (const float*)d_in[9], (const float*)d_in[13]};
  const float* b_out[3] = {(const float*)d_in[6], (const float*)d_in[10], (const float*)d_in[14]};
  const float* w_fuse = (const float*)d_in[15];
  const float* b_fuse = (const float*)d_in[16];
  const float* ln_g = (const float*)d_in[17];
  const float* ln_b = (const float*)d_in[18];

  auto A256 = [](size_t b) { return (b + 255) & ~(size_t)255; };
  const size_t EE = (size_t)E_DIM * E_DIM;

  const size_t persist = 3 * A256(5 * EE * 2) + 3 * A256(5 * E_DIM * 4) +
                         A256(3 * EE * 2) + A256(E_DIM * 4);

  // Preferred: CH=2048 chunks for proj/combine + FULL Ocat (one final GEMM).
  int CH = 2048;
  bool bigOcat;
  {
    size_t need = persist + 3 * A256((size_t)CH * E_DIM * 2) +
                  3 * A256((size_t)CH * 5 * E_DIM * 2) +
                  A256((size_t)B_ROWS * 3 * E_DIM * 2);
    bigOcat = (need <= ws_size);
  }
  if (!bigOcat) {
    CH = B_ROWS;
    while (CH > 256) {
      size_t pool = 3 * A256((size_t)CH * E_DIM * 2) + 3 * A256((size_t)CH * 5 * E_DIM * 2) +
                    A256((size_t)CH * 3 * E_DIM * 2);
      if (persist + pool <= ws_size) break;
      CH -= 256;
    }
  }

  char* p = (char*)d_ws;
  auto alloc = [&](size_t bytes) {
    void* r = (void*)p;
    p += A256(bytes);
    return r;
  };

  u16* Wcat[3];
  for (int i = 0; i < 3; i++) Wcat[i] = (u16*)alloc(5 * EE * 2);   // contiguous, stride 5EE
  float* bcat[3];
  for (int i = 0; i < 3; i++) bcat[i] = (float*)alloc(5 * E_DIM * 4);  // contiguous, stride 5120
  u16* Mcat = (u16*)alloc(3 * EE * 2);
  float* cb = (float*)alloc(E_DIM * 4);

  char* pool = p;

  // ---- stage 0: all Wcat in ONE launch + all bcat in ONE launch ----
  cvt_wcat<<<2048, 256, 0, stream>>>(w_in[0], w_in[1], w_in[2], Wcat[0]);
  concat_bias3<<<60, 256, 0, stream>>>(b_in[0], b_in[1], b_in[2], bcat[0]);

  // ---- stage 1: Mcat slices (ONE batched GEMM over f) + folded bias ----
  {
    u16* wfusebf = (u16*)pool;
    u16* woutT0 = (u16*)(pool + A256(3 * EE * 2));
    const long jsWT = (long)(A256(EE * 2) / 2);  // woutT stride (elements)
    cvt_f32_bf16<<<1024, 256, 0, stream>>>(w_fuse, wfusebf, (int)(3 * EE / 4));
    dim3 tb(32, 8);
    for (int f = 0; f < 3; f++)
      transpose_to_bf16<<<dim3(E_DIM / 32, E_DIM / 32), tb, 0, stream>>>(
          w_out[f], woutT0 + f * jsWT, E_DIM);
    // batched over f: Mcat[:, f*E:(f+1)E] = w_fuse[:, fE:(f+1)E] @ w_out_f
    gemm256<0><<<48, 512, 0, stream>>>(
        wfusebf, woutT0, (void*)Mcat, nullptr,
        3 * E_DIM, E_DIM, 3 * E_DIM, E_DIM, E_DIM / BN, 16,
        (long)E_DIM, jsWT, (long)E_DIM, 0);
    fold_bias<<<E_DIM / 4, 256, 0, stream>>>(b_out[0], b_out[1], b_out[2], w_fuse, b_fuse, cb);
  }

  // ---- stage 2: chunk loop ----
  {
    char* q = pool;
    auto palloc = [&](size_t bytes) {
      void* r = (void*)q;
      q += A256(bytes);
      return r;
    };
    u16* fb0 = (u16*)palloc(3 * A256((size_t)CH * E_DIM * 2));
    u16* P0 = (u16*)palloc(3 * A256((size_t)CH * 5 * E_DIM * 2));
    u16* Ocat = (u16*)palloc(bigOcat ? (size_t)B_ROWS * 3 * E_DIM * 2
                                     : (size_t)CH * 3 * E_DIM * 2);
    const long jsA = (long)CH * E_DIM;            // fb stride (elements)
    const long jsP = (long)CH * 5 * E_DIM;        // P stride (elements)
    const long jsW = (long)(A256(5 * EE * 2) / 2);
    const long jsB = 5 * E_DIM;

    for (int row0 = 0; row0 < B_ROWS; row0 += CH) {
      int rows = B_ROWS - row0 < CH ? B_ROWS - row0 : CH;
      cvt3_f32_bf16<<<1024, 256, 0, stream>>>(
          feat[0] + (size_t)row0 * E_DIM, feat[1] + (size_t)row0 * E_DIM,
          feat[2] + (size_t)row0 * E_DIM, fb0, fb0 + jsA, fb0 + 2 * jsA,
          rows * (E_DIM / 4));
      // merged projection: P[j] = fb[j] @ Wcat_j^T + bcat_j   [rows, 5120]
      const int njb = (rows / BM) * (5 * E_DIM / BN);
      gemm256<0><<<3 * njb, 512, 0, stream>>>(
          fb0, Wcat[0], (void*)P0, bcat[0], E_DIM, E_DIM, 5 * E_DIM, E_DIM,
          5 * E_DIM / BN, njb, jsA, jsW, jsP, jsB);
      // softmax-combine (all 3 MHAs, vectorized) into Ocat rows [row0, row0+rows)
      u16* Oc = bigOcat ? Ocat + (size_t)row0 * 3 * E_DIM : Ocat;
      attn_combine3<<<rows * H_N / 32, 256, 0, stream>>>(P0, jsP, Oc);
      if (!bigOcat) {
        int nt2 = (rows / BM) * (E_DIM / BN);
        gemm256<1><<<nt2, 512, 0, stream>>>(
            Ocat, Mcat, (void*)((float*)d_out + (size_t)row0 * E_DIM), cb,
            3 * E_DIM, 3 * E_DIM, E_DIM, 3 * E_DIM, E_DIM / BN, nt2, 0, 0, 0, 0);
      }
    }
    if (bigOcat) {
      int nt2 = (B_ROWS / BM) * (E_DIM / BN);  // 256 = exactly one machine round
      gemm256<1><<<nt2, 512, 0, stream>>>(
          Ocat, Mcat, d_out, cb, 3 * E_DIM, 3 * E_DIM, E_DIM, 3 * E_DIM,
          E_DIM / BN, nt2, 0, 0, 0, 0);
    }
  }

  // ---- stage 3: layernorm in place on d_out ----
  layernorm_inplace<<<B_ROWS, 256, 0, stream>>>((float*)d_out, ln_g, ln_b);
}

// Round 16
// 893.898 us; speedup vs baseline: 1.2644x; 1.0203x over previous
//
#include <hip/hip_runtime.h>
#include <stdint.h>

#define B_ROWS 16384
#define E_DIM 1024
#define H_N 16

typedef unsigned short u16;
typedef __attribute__((ext_vector_type(4))) float f32x4;
typedef __attribute__((ext_vector_type(4))) unsigned short u16x4;
typedef __attribute__((ext_vector_type(8))) short bf16x8;

static __device__ __forceinline__ u16 f2bf(float f) {
  union { float f; unsigned u; } x; x.f = f;
  unsigned r = (x.u + 0x7FFFu + ((x.u >> 16) & 1u)) >> 16;
  return (u16)r;
}
static __device__ __forceinline__ float bf2f(u16 h) {
  union { unsigned u; float f; } x; x.u = ((unsigned)h) << 16;
  return x.f;
}

typedef const __attribute__((address_space(1))) void gvoid;
typedef __attribute__((address_space(3))) void lvoid;
static __device__ __forceinline__ void gload16(const void* g, void* l) {
  __builtin_amdgcn_global_load_lds((gvoid*)g, (lvoid*)l, 16, 0, 0);
}

// ---------------- f32 -> bf16 convert (single buffer) ----------------
__global__ __launch_bounds__(256) void cvt_f32_bf16(const float* __restrict__ in,
                                                    u16* __restrict__ out, int n4) {
  int stride = gridDim.x * blockDim.x;
  for (int i = blockIdx.x * blockDim.x + threadIdx.x; i < n4; i += stride) {
    f32x4 v = ((const f32x4*)in)[i];
    u16x4 o;
    o.x = f2bf(v.x); o.y = f2bf(v.y); o.z = f2bf(v.z); o.w = f2bf(v.w);
    ((u16x4*)out)[i] = o;
  }
}

// ---------------- build ALL THREE Wcat_j = [wq_j ; wkv_o0 ; wkv_o1] in one launch
__global__ __launch_bounds__(256) void cvt_wcat(const float* __restrict__ w0,
                                                const float* __restrict__ w1,
                                                const float* __restrict__ w2,
                                                u16* __restrict__ out) {
  const float* W[3] = {w0, w1, w2};
  const int o0t[3] = {1, 0, 0}, o1t[3] = {2, 2, 1};
  const int EE4 = E_DIM * E_DIM / 4;
  const int n4per = 5 * EE4;
  const int total = 3 * n4per;
  int stride = gridDim.x * blockDim.x;
  for (int i = blockIdx.x * blockDim.x + threadIdx.x; i < total; i += stride) {
    int j = (i < n4per) ? 0 : (i < 2 * n4per ? 1 : 2);
    int r = i - j * n4per;
    const float* src;
    if (r < EE4) src = W[j] + 4 * (size_t)r;
    else if (r < 3 * EE4) src = W[o0t[j]] + 4 * (size_t)r;
    else src = W[o1t[j]] + 4 * (size_t)r - 2 * (size_t)E_DIM * E_DIM;
    f32x4 v = *(const f32x4*)src;
    u16x4 o;
    o.x = f2bf(v.x); o.y = f2bf(v.y); o.z = f2bf(v.z); o.w = f2bf(v.w);
    ((u16x4*)out)[(size_t)j * n4per + r] = o;
  }
}

// ---------------- f32 -> bf16 convert, 3 feature buffers in one launch ----------
__global__ __launch_bounds__(256) void cvt3_f32_bf16(const float* __restrict__ i0,
                                                     const float* __restrict__ i1,
                                                     const float* __restrict__ i2,
                                                     u16* __restrict__ o0,
                                                     u16* __restrict__ o1,
                                                     u16* __restrict__ o2, int n4) {
  int stride = gridDim.x * blockDim.x;
  for (int i = blockIdx.x * blockDim.x + threadIdx.x; i < n4; i += stride) {
    f32x4 a = ((const f32x4*)i0)[i];
    f32x4 b = ((const f32x4*)i1)[i];
    f32x4 c = ((const f32x4*)i2)[i];
    u16x4 x, y, z;
    x.x = f2bf(a.x); x.y = f2bf(a.y); x.z = f2bf(a.z); x.w = f2bf(a.w);
    y.x = f2bf(b.x); y.y = f2bf(b.y); y.z = f2bf(b.z); y.w = f2bf(b.w);
    z.x = f2bf(c.x); z.y = f2bf(c.y); z.z = f2bf(c.z); z.w = f2bf(c.w);
    ((u16x4*)o0)[i] = x;
    ((u16x4*)o1)[i] = y;
    ((u16x4*)o2)[i] = z;
  }
}

// ---------------- transpose f32 [n x n] -> bf16 [n x n]^T ----------------
__global__ __launch_bounds__(256) void transpose_to_bf16(const float* __restrict__ in,
                                                         u16* __restrict__ out, int n) {
  __shared__ float t[32][33];
  int bx = blockIdx.x * 32;
  int by = blockIdx.y * 32;
  int tx = threadIdx.x, ty = threadIdx.y;  // 32 x 8
  for (int r = ty; r < 32; r += 8)
    t[r][tx] = in[(size_t)(by + r) * n + bx + tx];
  __syncthreads();
  for (int r = ty; r < 32; r += 8)
    out[(size_t)(bx + r) * n + by + tx] = f2bf(t[tx][r]);
}

// ---------------- folded bias ----------------
__global__ __launch_bounds__(256) void fold_bias(const float* __restrict__ b0,
                                                 const float* __restrict__ b1,
                                                 const float* __restrict__ b2,
                                                 const float* __restrict__ wfuse,
                                                 const float* __restrict__ bfuse,
                                                 float* __restrict__ cb) {
  int wave = threadIdx.x >> 6, lane = threadIdx.x & 63;
  int j = blockIdx.x * 4 + wave;
  const float* wrow = wfuse + (size_t)j * (3 * E_DIM);
  float s = 0.f;
  for (int i = lane; i < E_DIM; i += 64) s += b0[i] * wrow[i];
  for (int i = lane; i < E_DIM; i += 64) s += b1[i] * wrow[E_DIM + i];
  for (int i = lane; i < E_DIM; i += 64) s += b2[i] * wrow[2 * E_DIM + i];
  for (int off = 32; off; off >>= 1) s += __shfl_xor(s, off);
  if (lane == 0) cb[j] = bfuse[j] + s;
}

// ---------------- concat bias, all 3 j in one launch (out stride 5120) --------
__global__ __launch_bounds__(256) void concat_bias3(const float* __restrict__ b0,
                                                    const float* __restrict__ b1,
                                                    const float* __restrict__ b2,
                                                    float* __restrict__ out) {
  const float* B[3] = {b0, b1, b2};
  const int o0t[3] = {1, 0, 0}, o1t[3] = {2, 2, 1};
  int j = blockIdx.x / 20;
  int i = (blockIdx.x % 20) * 256 + threadIdx.x;  // 5120 per j
  float v;
  if (i < 1024) v = B[j][i];
  else if (i < 3072) v = B[o0t[j]][i];
  else v = B[o1t[j]][i - 2048];
  out[(size_t)j * 5120 + i] = v;
}

// ================= GEMM 256x256x64, 8 waves, 4-phase/K-tile =================
// R16 = R15 ledger + COUNTED lgkmcnt (m201's trick): each phase issues its
// successor's ds_reads BEFORE the MFMA cluster, then waits with lgkmcnt(N)
// where N = the just-issued batch -- so only OLDER reads are forced and the
// new batch's latency hides under this phase's 16 MFMAs.
// Per-phase: P0: stage A0',B0'; VMC(4) [forces B1(cur), 3-ph lead, cheap];
//            BAR; read b1(4); lgkmcnt(4) [forces P3's 12 pre-reads]; Q00.
//            P1: stage A1',B1'; read a1(8); lgkmcnt(8) [forces b1]; Q01.
//            P2: lgkmcnt(0) [forces a1]; Q10.
//            P3: Q11 (all forced); VMC(2) [forces A0',A1',B0'; B1' floats];
//            BAR; pre-read a0',b0' (12) -- covered until next P0's lgkmcnt(4).
// A-half rule (R10/R14 lesson): RDA reads the wave's OWN half for both qm ->
// every wait preceding an a0-read forces BOTH A stages (VMC(2), not 4).
// WAR: all reads complete via counted waits before the barrier that precedes
// any overwrite of their region. Tails: P0 else-VMC(0); P3 pf-gated.
#define BM 256
#define BN 256
#define BK 64

#define RDA(buf, qm, dst)                                                         \
  do {                                                                            \
    _Pragma("unroll") for (int m = 0; m < 4; m++)                                 \
    _Pragma("unroll") for (int kk = 0; kk < 2; kk++) {                            \
      int rl = (qm)*64 + m * 16 + l16;                                            \
      int col = ((kk * 64 + kq * 16) ^ ((l16 & 7) << 4)) >> 1;                    \
      dst[m][kk] = *(const bf16x8*)&lds[buf][wm * 8192 + rl * 64 + col];          \
    }                                                                             \
  } while (0)

#define RDB(buf, qn, dst)                                                         \
  do {                                                                            \
    _Pragma("unroll") for (int n = 0; n < 2; n++)                                 \
    _Pragma("unroll") for (int kk = 0; kk < 2; kk++) {                            \
      int rt = (qn)*128 + wn * 32 + n * 16 + l16; /* B half = qn ONLY */          \
      int col = ((kk * 64 + kq * 16) ^ ((l16 & 7) << 4)) >> 1;                    \
      dst[n][kk] = *(const bf16x8*)&lds[buf][16384 + (rt >> 7) * 8192 +           \
                                             (rt & 127) * 64 + col];              \
    }                                                                             \
  } while (0)

#define MMAQ(qm, qn, A_, B_)                                                      \
  do {                                                                            \
    __builtin_amdgcn_s_setprio(1);                                                \
    _Pragma("unroll") for (int m = 0; m < 4; m++)                                 \
    _Pragma("unroll") for (int n = 0; n < 2; n++)                                 \
    _Pragma("unroll") for (int kk = 0; kk < 2; kk++)                              \
      acc[(qm)*4 + m][(qn)*2 + n] = __builtin_amdgcn_mfma_f32_16x16x32_bf16(      \
          A_[m][kk], B_[n][kk], acc[(qm)*4 + m][(qn)*2 + n], 0, 0, 0);            \
    __builtin_amdgcn_s_setprio(0);                                                \
  } while (0)

#define BAR() __builtin_amdgcn_s_barrier()
#define SCHED() __builtin_amdgcn_sched_barrier(0)
#define LGKM(n) asm volatile("s_waitcnt lgkmcnt(" #n ")" ::: "memory")
#define VMC(n) asm volatile("s_waitcnt vmcnt(" #n ")" ::: "memory")

template <int MODE>
__global__ __launch_bounds__(512, 2) void gemm256(const u16* __restrict__ A,
                                                  const u16* __restrict__ W,
                                                  void* __restrict__ Cp,
                                                  const float* __restrict__ bias,
                                                  int lda, int ldw, int ldc, int K,
                                                  int nbn, int njb,
                                                  long jsA, long jsW, long jsC, long jsB) {
  __shared__ __align__(16) u16 lds[2][32768];  // 128 KB

  const int tid = threadIdx.x;
  const int wave = tid >> 6;
  const int lane = tid & 63;
  const int wm = wave >> 2;   // 0..1: 128-row half (reads A half wm only)
  const int wn = wave & 3;    // 0..3: 32-col subgroup within each B half
  const int l16 = lane & 15;
  const int kq = lane >> 4;

  // T1: bijective XCD-aware block swizzle (static grid -> locality preserved)
  const int nwg = gridDim.x;
  int bid = blockIdx.x;
  int xcd = bid & 7, orig = bid >> 3;
  int q8 = nwg >> 3, r8 = nwg & 7;
  int wg = (xcd < r8 ? xcd * (q8 + 1) : r8 * (q8 + 1) + (xcd - r8) * q8) + orig;
  const int j = wg / njb;
  const int rem = wg - j * njb;
  const int bm = rem / nbn;
  const int bn = rem % nbn;

  const u16* Ab = A + j * jsA + (size_t)bm * BM * lda;
  const u16* Wb = W + j * jsW + (size_t)bn * BN * ldw;

  f32x4 acc[8][4];
#pragma unroll
  for (int i = 0; i < 8; i++)
#pragma unroll
    for (int n = 0; n < 4; n++) acc[i][n] = (f32x4){0.f, 0.f, 0.f, 0.f};

  // stage one half-tile: 0=A0,1=A1,2=B0,3=B1 (base = which*8192 el)
  auto stageH = [&](int buf, int which, int k0) {
    const u16* src = (which >= 2) ? Wb : Ab;
    const int ld = (which >= 2) ? ldw : lda;
    const int h = which & 1;
#pragma unroll
    for (int r = 0; r < 2; r++) {
      int slot = r * 512 + tid;               // 1024 slots = 128 rows x 8 chunks
      int row = h * 128 + (slot >> 3);
      int col = ((slot & 7) ^ (row & 7)) * 8; // pre-swizzled source (involution)
      gload16(src + (size_t)row * ld + k0 + col, &lds[buf][which * 8192 + slot * 8]);
    }
  };

  const int nt = K / BK;

  // prologue: stage [A0,B0,A1,B1]; vmcnt(2) forces A0,B0,A1 (B1 floats);
  // pre-read a0 (touches A0+A1 per wm), b0.
  stageH(0, 0, 0); stageH(0, 2, 0); stageH(0, 1, 0); stageH(0, 3, 0);
  VMC(2);
  BAR();
  SCHED();

  bf16x8 a0[4][2], a1[4][2], b0[2][2], b1[2][2];
  RDA(0, 0, a0);
  RDB(0, 0, b0);

  int cur = 0;
  for (int t = 0; t < nt; ++t) {
    const bool pf = (t + 1 < nt);
    const int nb = cur ^ 1;
    const int nk = (t + 1) * BK;
    // ---- P0: stage A0',B0'; force B1(cur) [cheap: 3-ph lead]; read b1;
    //          counted lgkm forces P3's 12 pre-reads; MFMA Q(0,0) ----
    if (pf) { stageH(nb, 0, nk); stageH(nb, 2, nk); }
    if (pf) VMC(4); else VMC(0);   // forces B1(cur) [staged P1(t-1)]
    BAR();
    SCHED();
    RDB(cur, 1, b1);               // 4 reads; float under Q00
    LGKM(4);                       // forces a0,b0 (12 pre-reads from P3)
    SCHED();
    MMAQ(0, 0, a0, b0);
    // ---- P1: stage A1',B1'; read a1 (A fully forced); lgkm(8) forces b1;
    //          MFMA Q(0,1) ----
    if (pf) { stageH(nb, 1, nk); stageH(nb, 3, nk); }
    RDA(cur, 1, a1);               // 8 reads; float under Q01
    LGKM(8);                       // forces b1 (covered by Q00)
    SCHED();
    MMAQ(0, 1, a0, b1);
    // ---- P2: lgkm(0) forces a1 (covered by Q01); MFMA Q(1,0) ----
    LGKM(0);
    SCHED();
    MMAQ(1, 0, a1, b0);
    // ---- P3: MFMA Q(1,1) (operands forced); then force A0',A1',B0';
    //          pre-read a0',b0' (covered until next P0's lgkm(4)) ----
    SCHED();
    MMAQ(1, 1, a1, b1);
    if (pf) {
      VMC(2);                      // forces A0',B0',A1' (B1' floats to next P0)
      BAR();
      SCHED();
      RDA(nb, 0, a0);              // touches A0'+A1' per wm -- both forced
      RDB(nb, 0, b0);
    }
    cur ^= 1;
  }

  const int r0 = kq * 4;  // C/D: col = lane&15, row = (lane>>4)*4 + r
#pragma unroll
  for (int mf = 0; mf < 8; mf++) {
#pragma unroll
    for (int nf = 0; nf < 4; nf++) {
      int row = bm * BM + wm * 128 + mf * 16 + r0;
      int col = bn * BN + (nf >> 1) * 128 + wn * 32 + (nf & 1) * 16 + l16;
      if (MODE == 0) {
        u16* C = (u16*)Cp + j * jsC;
        float bv = bias ? bias[j * jsB + col] : 0.f;
#pragma unroll
        for (int r = 0; r < 4; r++)
          C[(size_t)(row + r) * ldc + col] = f2bf(acc[mf][nf][r] + bv);
      } else {
        float* C = (float*)Cp + j * jsC;
        float bv = bias[j * jsB + col];
#pragma unroll
        for (int r = 0; r < 4; r++)
          C[(size_t)(row + r) * ldc + col] = acc[mf][nf][r] + bv;
      }
    }
  }
}

// ---------------- attention combine: all 3 MHAs, VECTORIZED (bf16x8/lane) -----
__global__ __launch_bounds__(256) void attn_combine3(const u16* __restrict__ Pb,
                                                     long jsP, u16* __restrict__ Oc) {
  int grp = blockIdx.x * 32 + (threadIdx.x >> 3);  // (b,h) group
  int l8 = threadIdx.x & 7;
  int b = grp >> 4, h = grp & 15;
  size_t prow = (size_t)b * 5120;
  int dbase = h * 64 + l8 * 8;
  const int j1a[3] = {1, 0, 0}, j2a[3] = {2, 2, 1};
  const int offA[3] = {1024, 1024, 3072}, offB[3] = {1024, 3072, 3072};
#pragma unroll
  for (int m = 0; m < 3; m++) {
    const u16* Pq = Pb + m * jsP;
    const u16* Pa = Pb + j1a[m] * jsP;
    const u16* Pc = Pb + j2a[m] * jsP;
    bf16x8 qv = *(const bf16x8*)&Pq[prow + dbase];
    bf16x8 k1 = *(const bf16x8*)&Pa[prow + offA[m] + dbase];
    bf16x8 v1 = *(const bf16x8*)&Pa[prow + offA[m] + 1024 + dbase];
    bf16x8 k2 = *(const bf16x8*)&Pc[prow + offB[m] + dbase];
    bf16x8 v2 = *(const bf16x8*)&Pc[prow + offB[m] + 1024 + dbase];
    float s1 = 0.f, s2 = 0.f;
#pragma unroll
    for (int e = 0; e < 8; e++) {
      float q = bf2f((u16)qv[e]);
      s1 += q * bf2f((u16)k1[e]);
      s2 += q * bf2f((u16)k2[e]);
    }
    s1 += __shfl_xor(s1, 1); s1 += __shfl_xor(s1, 2); s1 += __shfl_xor(s1, 4);
    s2 += __shfl_xor(s2, 1); s2 += __shfl_xor(s2, 2); s2 += __shfl_xor(s2, 4);
    s1 *= 0.125f; s2 *= 0.125f;  // 1/sqrt(64)
    float mx = fmaxf(s1, s2);
    float e1 = __expf(s1 - mx), e2 = __expf(s2 - mx);
    float rn = 1.f / (e1 + e2);
    float w1 = e1 * rn, w2 = e2 * rn;
    bf16x8 ov;
#pragma unroll
    for (int e = 0; e < 8; e++)
      ov[e] = (short)f2bf(w1 * bf2f((u16)v1[e]) + w2 * bf2f((u16)v2[e]));
    *(bf16x8*)&Oc[(size_t)b * 3072 + m * 1024 + dbase] = ov;
  }
}

// ---------------- layernorm in place on f32 [B,1024] ----------------
__global__ __launch_bounds__(256) void layernorm_inplace(float* __restrict__ y,
                                                         const float* __restrict__ g,
                                                         const float* __restrict__ b) {
  int row = blockIdx.x, tid = threadIdx.x;
  float* yr = y + (size_t)row * E_DIM;
  f32x4 v = ((const f32x4*)yr)[tid];
  float s = v.x + v.y + v.z + v.w;
  float sq = v.x * v.x + v.y * v.y + v.z * v.z + v.w * v.w;
  for (int off = 32; off; off >>= 1) {
    s += __shfl_xor(s, off);
    sq += __shfl_xor(sq, off);
  }
  __shared__ float rs[4], rq[4];
  int wave = tid >> 6, lane = tid & 63;
  if (lane == 0) { rs[wave] = s; rq[wave] = sq; }
  __syncthreads();
  s = rs[0] + rs[1] + rs[2] + rs[3];
  sq = rq[0] + rq[1] + rq[2] + rq[3];
  float mu = s * (1.f / E_DIM);
  float var = sq * (1.f / E_DIM) - mu * mu;
  float rstd = rsqrtf(var + 1e-5f);
  f32x4 gg = ((const f32x4*)g)[tid];
  f32x4 bb = ((const f32x4*)b)[tid];
  f32x4 o;
  o.x = (v.x - mu) * rstd * gg.x + bb.x;
  o.y = (v.y - mu) * rstd * gg.y + bb.y;
  o.z = (v.z - mu) * rstd * gg.z + bb.z;
  o.w = (v.w - mu) * rstd * gg.w + bb.w;
  ((f32x4*)yr)[tid] = o;
}

extern "C" void kernel_launch(void* const* d_in, const int* in_sizes, int n_in,
                              void* d_out, int out_size, void* d_ws, size_t ws_size,
                              hipStream_t stream) {
  const float* feat[3] = {(const float*)d_in[0], (const float*)d_in[1], (const float*)d_in[2]};
  const float* w_in[3] = {(const float*)d_in[3], (const float*)d_in[7], (const float*)d_in[11]};
  const float* b_in[3] = {(const float*)d_in[4], (const float*)d_in[8], (const float*)d_in[12]};
  const float* w_out[3] = {(const float*)d_in[5], (const float*)d_in[9], (const float*)d_in[13]};
  const float* b_out[3] = {(const float*)d_in[6], (const float*)d_in[10], (const float*)d_in[14]};
  const float* w_fuse = (const float*)d_in[15];
  const float* b_fuse = (const float*)d_in[16];
  const float* ln_g = (const float*)d_in[17];
  const float* ln_b = (const float*)d_in[18];

  auto A256 = [](size_t b) { return (b + 255) & ~(size_t)255; };
  const size_t EE = (size_t)E_DIM * E_DIM;

  const size_t persist = 3 * A256(5 * EE * 2) + 3 * A256(5 * E_DIM * 4) +
                         A256(3 * EE * 2) + A256(E_DIM * 4);

  // Preferred: CH=2048 chunks for proj/combine + FULL Ocat (one final GEMM).
  int CH = 2048;
  bool bigOcat;
  {
    size_t need = persist + 3 * A256((size_t)CH * E_DIM * 2) +
                  3 * A256((size_t)CH * 5 * E_DIM * 2) +
                  A256((size_t)B_ROWS * 3 * E_DIM * 2);
    bigOcat = (need <= ws_size);
  }
  if (!bigOcat) {
    CH = B_ROWS;
    while (CH > 256) {
      size_t pool = 3 * A256((size_t)CH * E_DIM * 2) + 3 * A256((size_t)CH * 5 * E_DIM * 2) +
                    A256((size_t)CH * 3 * E_DIM * 2);
      if (persist + pool <= ws_size) break;
      CH -= 256;
    }
  }

  char* p = (char*)d_ws;
  auto alloc = [&](size_t bytes) {
    void* r = (void*)p;
    p += A256(bytes);
    return r;
  };

  u16* Wcat[3];
  for (int i = 0; i < 3; i++) Wcat[i] = (u16*)alloc(5 * EE * 2);   // contiguous, stride 5EE
  float* bcat[3];
  for (int i = 0; i < 3; i++) bcat[i] = (float*)alloc(5 * E_DIM * 4);  // contiguous, stride 5120
  u16* Mcat = (u16*)alloc(3 * EE * 2);
  float* cb = (float*)alloc(E_DIM * 4);

  char* pool = p;

  // ---- stage 0: all Wcat in ONE launch + all bcat in ONE launch ----
  cvt_wcat<<<2048, 256, 0, stream>>>(w_in[0], w_in[1], w_in[2], Wcat[0]);
  concat_bias3<<<60, 256, 0, stream>>>(b_in[0], b_in[1], b_in[2], bcat[0]);

  // ---- stage 1: Mcat slices (ONE batched GEMM over f) + folded bias ----
  {
    u16* wfusebf = (u16*)pool;
    u16* woutT0 = (u16*)(pool + A256(3 * EE * 2));
    const long jsWT = (long)(A256(EE * 2) / 2);  // woutT stride (elements)
    cvt_f32_bf16<<<1024, 256, 0, stream>>>(w_fuse, wfusebf, (int)(3 * EE / 4));
    dim3 tb(32, 8);
    for (int f = 0; f < 3; f++)
      transpose_to_bf16<<<dim3(E_DIM / 32, E_DIM / 32), tb, 0, stream>>>(
          w_out[f], woutT0 + f * jsWT, E_DIM);
    // batched over f: Mcat[:, f*E:(f+1)E] = w_fuse[:, fE:(f+1)E] @ w_out_f
    gemm256<0><<<48, 512, 0, stream>>>(
        wfusebf, woutT0, (void*)Mcat, nullptr,
        3 * E_DIM, E_DIM, 3 * E_DIM, E_DIM, E_DIM / BN, 16,
        (long)E_DIM, jsWT, (long)E_DIM, 0);
    fold_bias<<<E_DIM / 4, 256, 0, stream>>>(b_out[0], b_out[1], b_out[2], w_fuse, b_fuse, cb);
  }

  // ---- stage 2: chunk loop ----
  {
    char* q = pool;
    auto palloc = [&](size_t bytes) {
      void* r = (void*)q;
      q += A256(bytes);
      return r;
    };
    u16* fb0 = (u16*)palloc(3 * A256((size_t)CH * E_DIM * 2));
    u16* P0 = (u16*)palloc(3 * A256((size_t)CH * 5 * E_DIM * 2));
    u16* Ocat = (u16*)palloc(bigOcat ? (size_t)B_ROWS * 3 * E_DIM * 2
                                     : (size_t)CH * 3 * E_DIM * 2);
    const long jsA = (long)CH * E_DIM;            // fb stride (elements)
    const long jsP = (long)CH * 5 * E_DIM;        // P stride (elements)
    const long jsW = (long)(A256(5 * EE * 2) / 2);
    const long jsB = 5 * E_DIM;

    for (int row0 = 0; row0 < B_ROWS; row0 += CH) {
      int rows = B_ROWS - row0 < CH ? B_ROWS - row0 : CH;
      cvt3_f32_bf16<<<1024, 256, 0, stream>>>(
          feat[0] + (size_t)row0 * E_DIM, feat[1] + (size_t)row0 * E_DIM,
          feat[2] + (size_t)row0 * E_DIM, fb0, fb0 + jsA, fb0 + 2 * jsA,
          rows * (E_DIM / 4));
      // merged projection: P[j] = fb[j] @ Wcat_j^T + bcat_j   [rows, 5120]
      const int njb = (rows / BM) * (5 * E_DIM / BN);
      gemm256<0><<<3 * njb, 512, 0, stream>>>(
          fb0, Wcat[0], (void*)P0, bcat[0], E_DIM, E_DIM, 5 * E_DIM, E_DIM,
          5 * E_DIM / BN, njb, jsA, jsW, jsP, jsB);
      // softmax-combine (all 3 MHAs, vectorized) into Ocat rows [row0, row0+rows)
      u16* Oc = bigOcat ? Ocat + (size_t)row0 * 3 * E_DIM : Ocat;
      attn_combine3<<<rows * H_N / 32, 256, 0, stream>>>(P0, jsP, Oc);
      if (!bigOcat) {
        int nt2 = (rows / BM) * (E_DIM / BN);
        gemm256<1><<<nt2, 512, 0, stream>>>(
            Ocat, Mcat, (void*)((float*)d_out + (size_t)row0 * E_DIM), cb,
            3 * E_DIM, 3 * E_DIM, E_DIM, 3 * E_DIM, E_DIM / BN, nt2, 0, 0, 0, 0);
      }
    }
    if (bigOcat) {
      int nt2 = (B_ROWS / BM) * (E_DIM / BN);  // 256 = exactly one machine round
      gemm256<1><<<nt2, 512, 0, stream>>>(
          Ocat, Mcat, d_out, cb, 3 * E_DIM, 3 * E_DIM, E_DIM, 3 * E_DIM,
          E_DIM / BN, nt2, 0, 0, 0, 0);
    }
  }

  // ---- stage 3: layernorm in place on d_out ----
  layernorm_inplace<<<B_ROWS, 256, 0, stream>>>((float*)d_out, ln_g, ln_b);
}